// Round 3
// baseline (252.751 us; speedup 1.0000x reference)
//
#include <hip/hip_runtime.h>
#include <math.h>

#define DD 160
#define HH 192
#define WW 160
#define TW 32          // voxels per block in w (16 lanes x 2 voxels)
#define TH 16          // rows per block
#define TD 8           // slices per block
#define HW (HH * WW)
#define NVOX (DD * HH * WW)
#define HTW 34         // halo width in w
#define HTH 18         // halo rows
#define HSTR 36        // padded LDS row stride (floats); halo stored at col 1..34
#define HALO (HTH * HTW)   // 612 elements per field per slice

// atan, |err| <= 0.0015 rad (Rajan et al. 2-coeff) + rcp range reduction.
// Final output is a mean of squared differences; 4x poly error contributes
// ~0.006 abs — threshold is 6.5e-2.
__device__ __forceinline__ float atan_fast(float r) {
    float ar = fabsf(r);
    bool big = ar > 1.0f;
    float inv = __builtin_amdgcn_rcpf(ar);
    float x = big ? inv : ar;
    float t = fmaf(0.0663f, x, 0.2447f);
    float p = x * fmaf(1.0f - x, t, 0.78539816f);
    float res = big ? (1.57079632679f - p) : p;
    return copysignf(res, r);
}

__global__ __launch_bounds__(256, 4) void demons_ori_kernel(
    const float* __restrict__ Mv, const float* __restrict__ Sv,
    const float* __restrict__ flow, float* __restrict__ out)
{
    // double-buffered raw slice per field; col 0 and 35 are pad so the
    // 2-voxel reads land on 8B-aligned ds_read_b64 (all conflict-free)
    __shared__ __attribute__((aligned(16))) float buf[2][2][HTH * HSTR];
    __shared__ float redbuf[4];

    const int tid = threadIdx.x;
    const int twt = tid & 15;        // w-thread (owns 2 voxels)
    const int th  = tid >> 4;        // row 0..15
    const int w0 = blockIdx.x * TW;
    const int h0 = blockIdx.y * TH;
    const int d0 = blockIdx.z * TD;

    // slice-invariant staging slots (<=3 per thread; 612 = 2*256 + 100)
    int nst = 0;
    int sidx[3], gbase[3];
    bool gok[3];
    for (int i = tid; i < HALO; i += 256) {
        int hh = i / HTW, ww = i - HTW * hh;
        sidx[nst] = hh * HSTR + ww + 1;
        int gh = h0 + hh - 1, gw = w0 + ww - 1;
        gok[nst] = (gh >= 0 && gh < HH && gw >= 0 && gw < WW);
        gbase[nst] = gh * WW + gw;
        nst++;
    }

    // prefetch slice d -> registers (latency hidden behind a full stage)
    float pfS[3], pfM[3];
    auto issue = [&](int d) {
        const bool din = (d >= 0) && (d < DD);
        #pragma unroll
        for (int j = 0; j < 3; ++j) {
            float vs = 0.f, vm = 0.f;
            if (j < nst && din && gok[j]) {
                size_t off = (size_t)d * HW + gbase[j];
                vs = Sv[off];
                vm = Mv[off];
            }
            pfS[j] = vs; pfM[j] = vm;
        }
    };
    // commit prefetched regs -> LDS parity d&1
    auto commit = [&](int d) {
        float* __restrict__ bS = &buf[d & 1][0][0];
        float* __restrict__ bM = &buf[d & 1][1][0];
        #pragma unroll
        for (int j = 0; j < 3; ++j)
            if (j < nst) { bS[sidx[j]] = pfS[j]; bM[sidx[j]] = pfM[j]; }
    };

    // separable in-plane partials for 2 voxels from LDS parity `par`
    // pq[f] = {Px (sobel-x), Py (sobel-y), B ([1,2,1]_h [1,1,1]_w)}[2 vox]
    // ctr[f] = center values (needed for Idiff), carried in registers
    const int rbase = th * HSTR + 2 * twt;
    auto partials = [&](int par, float pq[2][3][2], float ctr[2][2]) {
        #pragma unroll
        for (int f = 0; f < 2; ++f) {
            const float* __restrict__ b = &buf[par][f][0];
            const float* r0 = b + rbase;
            const float* r1 = r0 + HSTR;
            const float* r2 = r1 + HSTR;
            float2 A0 = *(const float2*)(r0);
            float2 B0 = *(const float2*)(r0 + 2);
            float2 C0 = *(const float2*)(r0 + 4);
            float2 A1 = *(const float2*)(r1);
            float2 B1 = *(const float2*)(r1 + 2);
            float2 C1 = *(const float2*)(r1 + 4);
            float2 A2 = *(const float2*)(r2);
            float2 B2 = *(const float2*)(r2 + 2);
            float2 C2 = *(const float2*)(r2 + 4);
            // row values v0..v3 = cols (2t+1 .. 2t+4) = A.y, B.x, B.y, C.x
            float X0a = B0.y - A0.y, X0b = C0.x - B0.x;
            float X1a = B1.y - A1.y, X1b = C1.x - B1.x;
            float X2a = B2.y - A2.y, X2b = C2.x - B2.x;
            float W0a = A0.y + 2.f * B0.x + B0.y, W0b = B0.x + 2.f * B0.y + C0.x;
            float W2a = A2.y + 2.f * B2.x + B2.y, W2b = B2.x + 2.f * B2.y + C2.x;
            float I0a = A0.y + B0.x + B0.y, I0b = B0.x + B0.y + C0.x;
            float I1a = A1.y + B1.x + B1.y, I1b = B1.x + B1.y + C1.x;
            float I2a = A2.y + B2.x + B2.y, I2b = B2.x + B2.y + C2.x;
            pq[f][0][0] = X0a + 2.f * X1a + X2a;
            pq[f][0][1] = X0b + 2.f * X1b + X2b;
            pq[f][1][0] = W2a - W0a;
            pq[f][1][1] = W2b - W0b;
            pq[f][2][0] = I0a + 2.f * I1a + I2a;
            pq[f][2][1] = I0b + 2.f * I1b + I2b;
            ctr[f][0] = B1.x; ctr[f][1] = B1.y;
        }
    };

    float Pm[2][3][2], P0[2][3][2], Pp[2][3][2];
    float Cc[2][2], Cn[2][2], Cj[2][2];

    // ---- warmup pipeline ----
    issue(d0 - 1); commit(d0 - 1);
    issue(d0);
    __syncthreads();
    partials((d0 - 1) & 1, Pm, Cj);
    commit(d0);
    issue(d0 + 1);
    __syncthreads();
    partials(d0 & 1, P0, Cc);

    const size_t voff0 = (size_t)(h0 + th) * WW + (w0 + 2 * twt);
    float2 Fx = *(const float2*)(flow + (size_t)d0 * HW + voff0);
    float2 Fy = *(const float2*)(flow + (size_t)NVOX + (size_t)d0 * HW + voff0);
    float2 Fz = *(const float2*)(flow + 2 * (size_t)NVOX + (size_t)d0 * HW + voff0);

    float lsum = 0.f;

    #pragma unroll
    for (int dd = 0; dd < TD; ++dd) {
        const int d = d0 + dd;
        commit(d + 1);                       // parity (d+1)&1 — safe vs laggards
        float2 nFx, nFy, nFz;
        if (dd < TD - 1) {
            issue(d + 2);                    // hidden behind this whole stage
            size_t foff = (size_t)(d + 1) * HW + voff0;
            nFx = *(const float2*)(flow + foff);
            nFy = *(const float2*)(flow + (size_t)NVOX + foff);
            nFz = *(const float2*)(flow + 2 * (size_t)NVOX + foff);
        }
        __syncthreads();
        partials((d + 1) & 1, Pp, Cn);

        #pragma unroll
        for (int v = 0; v < 2; ++v) {
            float idf = Cc[1][v] - Cc[0][v];
            float i2 = idf * idf + 1e-10f;
            float gxS = Pm[0][0][v] + P0[0][0][v] + Pp[0][0][v];
            float gyS = Pm[0][1][v] + P0[0][1][v] + Pp[0][1][v];
            float gzS = Pp[0][2][v] - Pm[0][2][v];
            float gxM = Pm[1][0][v] + P0[1][0][v] + Pp[1][0][v];
            float gyM = Pm[1][1][v] + P0[1][1][v] + Pp[1][1][v];
            float gzM = Pp[1][2][v] - Pm[1][2][v];
            float denS = gxS * gxS + gyS * gyS + gzS * gzS + i2;
            float denM = gxM * gxM + gyM * gyM + gzM * gzM + i2;
            float rS = __builtin_amdgcn_rcpf(denS);
            float rM = __builtin_amdgcn_rcpf(denM);
            float Ux = idf * (gxS * rS + gxM * rM);
            float Uy = idf * (gyS * rS + gyM * rM);
            float Uz = idf * (gzS * rS + gzM * rM);
            float rz = __builtin_amdgcn_rcpf(Uz + 1e-10f);
            float dxz = atan_fast(Ux * rz);
            float dyz = atan_fast(Uy * rz);
            float fx = v ? Fx.y : Fx.x;
            float fy = v ? Fy.y : Fy.x;
            float fz = v ? Fz.y : Fz.x;
            float rf = __builtin_amdgcn_rcpf(fz + 1e-10f);
            float fxz = atan_fast(fx * rf);
            float fyz = atan_fast(fy * rf);
            float e1 = fxz - dxz;
            float e2 = fyz - dyz;
            lsum += e1 * e1 + e2 * e2;
        }

        // rotate rings (full unroll -> register renaming, no movs)
        #pragma unroll
        for (int f = 0; f < 2; ++f) {
            #pragma unroll
            for (int q = 0; q < 3; ++q) {
                Pm[f][q][0] = P0[f][q][0]; Pm[f][q][1] = P0[f][q][1];
                P0[f][q][0] = Pp[f][q][0]; P0[f][q][1] = Pp[f][q][1];
            }
            Cc[f][0] = Cn[f][0]; Cc[f][1] = Cn[f][1];
        }
        if (dd < TD - 1) { Fx = nFx; Fy = nFy; Fz = nFz; }
    }

    // wave shuffle -> LDS across 4 waves -> one atomic per block
    #pragma unroll
    for (int o = 32; o > 0; o >>= 1)
        lsum += __shfl_down(lsum, o, 64);
    if ((tid & 63) == 0)
        redbuf[tid >> 6] = lsum;
    __syncthreads();
    if (tid == 0) {
        float s = redbuf[0] + redbuf[1] + redbuf[2] + redbuf[3];
        atomicAdd(out, s * (1.0f / (float)NVOX));
    }
}

extern "C" void kernel_launch(void* const* d_in, const int* in_sizes, int n_in,
                              void* d_out, int out_size, void* d_ws, size_t ws_size,
                              hipStream_t stream) {
    const float* Mv   = (const float*)d_in[0];
    const float* Sv   = (const float*)d_in[1];
    const float* flow = (const float*)d_in[2];
    float* out = (float*)d_out;

    hipMemsetAsync(out, 0, sizeof(float), stream);

    dim3 grid(WW / TW, HH / TH, DD / TD);   // 5 x 12 x 20 = 1200 blocks
    demons_ori_kernel<<<grid, dim3(256), 0, stream>>>(Mv, Sv, flow, out);
}

// Round 4
// 140.912 us; speedup vs baseline: 1.7937x; 1.7937x over previous
//
#include <hip/hip_runtime.h>
#include <math.h>

#define DD 160
#define HH 192
#define WW 160
#define TW 32
#define TH 8
#define TD 8
#define HW (HH * WW)
#define NVOX (DD * HW)
#define HTW 34
#define HTH 10
#define HALO (HTW * HTH)   // 340

// atan via odd minimax poly on [0,1] + rcp range reduction; max err ~1e-5 rad
__device__ __forceinline__ float atan_fast(float r) {
    float ar = fabsf(r);
    float inv = __builtin_amdgcn_rcpf(ar);
    bool big = ar > 1.0f;
    float x = big ? inv : ar;
    float x2 = x * x;
    float p = fmaf(x2, fmaf(x2, fmaf(x2, fmaf(x2, fmaf(x2,
              -0.0117212f, 0.05265332f), -0.11643287f), 0.19354346f),
              -0.33262347f), 0.99997726f);
    p *= x;
    float res = big ? (1.57079632679489662f - p) : p;
    return copysignf(res, r);
}

__global__ __launch_bounds__(256) void demons_ori_kernel(
    const float* __restrict__ Mv, const float* __restrict__ Sv,
    const float* __restrict__ flow, float* __restrict__ out)
{
    // double-buffered single raw slice per field (parity = d&1)
    __shared__ float buf[2][2][HTH][HTW];
    __shared__ float redbuf[4];

    const int tid = threadIdx.x;
    const int tw = tid & 31;
    const int th = tid >> 5;
    const int w0 = blockIdx.x * TW;
    const int h0 = blockIdx.y * TH;
    const int d0 = blockIdx.z * TD;

    // slice-invariant staging slots: slot0 = tid, slot1 = tid+256 (if <340)
    const bool has1 = (tid < HALO - 256);
    int idx0, gb0, idx1 = 0, gb1 = 0;
    bool ok0, ok1 = false;
    {
        int i = tid;
        int hh = i / HTW, ww = i - HTW * hh;
        int gh = h0 + hh - 1, gw = w0 + ww - 1;
        idx0 = i;
        ok0 = (gh >= 0 && gh < HH && gw >= 0 && gw < WW);
        gb0 = gh * WW + gw;
        if (has1) {
            i = tid + 256;
            hh = i / HTW; ww = i - HTW * hh;
            gh = h0 + hh - 1; gw = w0 + ww - 1;
            idx1 = i;
            ok1 = (gh >= 0 && gh < HH && gw >= 0 && gw < WW);
            gb1 = gh * WW + gw;
        }
    }

    // prefetch registers — NAMED SCALARS ONLY (round-3 lesson: array params
    // to lambdas decayed to pointers -> scratch spill, 168 MB WRITE_SIZE)
    float pS0 = 0.f, pM0 = 0.f, pS1 = 0.f, pM1 = 0.f;

    auto issue = [&](int d) {
        const bool din = (d >= 0) && (d < DD);
        const size_t base = (size_t)d * HW;
        pS0 = (din && ok0) ? Sv[base + gb0] : 0.f;
        pM0 = (din && ok0) ? Mv[base + gb0] : 0.f;
        pS1 = (din && ok1) ? Sv[base + gb1] : 0.f;
        pM1 = (din && ok1) ? Mv[base + gb1] : 0.f;
    };
    auto commit = [&](int d) {
        float* __restrict__ bS = &buf[d & 1][0][0][0];
        float* __restrict__ bM = &buf[d & 1][1][0][0];
        bS[idx0] = pS0;
        bM[idx0] = pM0;
        if (has1) { bS[idx1] = pS1; bM[idx1] = pM1; }
    };

    const int hc = th + 1, wc = tw + 1;
    // separable in-plane partials from LDS parity par:
    // pq[f] = {Px (sobel-x), Py (sobel-y), B (box), center}
    auto partials = [&](int par, float pq[2][4]) {
        #pragma unroll
        for (int f = 0; f < 2; ++f) {
            const float* __restrict__ b = &buf[par][f][0][0];
            const float* r0 = b + (hc - 1) * HTW + (wc - 1);
            const float* r1 = r0 + HTW;
            const float* r2 = r1 + HTW;
            float v00 = r0[0], v01 = r0[1], v02 = r0[2];
            float v10 = r1[0], v11 = r1[1], v12 = r1[2];
            float v20 = r2[0], v21 = r2[1], v22 = r2[2];
            pq[f][0] = (v02 + 2.f * v12 + v22) - (v00 + 2.f * v10 + v20);
            pq[f][1] = (v20 + 2.f * v21 + v22) - (v00 + 2.f * v01 + v02);
            pq[f][2] = (v00 + v01 + v02) + 2.f * (v10 + v11 + v12)
                     + (v20 + v21 + v22);
            pq[f][3] = v11;
        }
    };

    float Pm[2][4], P0[2][4], Pp[2][4];

    // ---- warmup pipeline ----
    issue(d0 - 1);
    commit(d0 - 1);          // only exposed vmcnt wait of the whole block
    issue(d0);
    __syncthreads();
    partials((d0 - 1) & 1, Pm);
    commit(d0);              // load latency hidden behind partials(Pm)
    issue(d0 + 1);
    __syncthreads();
    partials(d0 & 1, P0);

    const size_t voff0 = (size_t)(h0 + th) * WW + (w0 + tw);
    float fFx = flow[(size_t)d0 * HW + voff0];
    float fFy = flow[(size_t)NVOX + (size_t)d0 * HW + voff0];
    float fFz = flow[2 * (size_t)NVOX + (size_t)d0 * HW + voff0];

    float lsum = 0.f;

    #pragma unroll
    for (int dd = 0; dd < TD; ++dd) {
        const int d = d0 + dd;
        commit(d + 1);       // vmcnt wait for loads issued a full stage ago
        float nFx = 0.f, nFy = 0.f, nFz = 0.f;
        if (dd < TD - 1) {
            issue(d + 2);    // in flight across this whole stage
            size_t foff = (size_t)(d + 1) * HW + voff0;
            nFx = flow[foff];
            nFy = flow[(size_t)NVOX + foff];
            nFz = flow[2 * (size_t)NVOX + foff];
        }
        __syncthreads();
        partials((d + 1) & 1, Pp);

        float idf = P0[1][3] - P0[0][3];
        float i2 = idf * idf + 1e-10f;
        float gxS = Pm[0][0] + P0[0][0] + Pp[0][0];
        float gyS = Pm[0][1] + P0[0][1] + Pp[0][1];
        float gzS = Pp[0][2] - Pm[0][2];
        float gxM = Pm[1][0] + P0[1][0] + Pp[1][0];
        float gyM = Pm[1][1] + P0[1][1] + Pp[1][1];
        float gzM = Pp[1][2] - Pm[1][2];
        float denS = gxS * gxS + gyS * gyS + gzS * gzS + i2;
        float denM = gxM * gxM + gyM * gyM + gzM * gzM + i2;
        float rS = __builtin_amdgcn_rcpf(denS);
        float rM = __builtin_amdgcn_rcpf(denM);
        float Ux = idf * (gxS * rS + gxM * rM);
        float Uy = idf * (gyS * rS + gyM * rM);
        float Uz = idf * (gzS * rS + gzM * rM);
        float rz = __builtin_amdgcn_rcpf(Uz + 1e-10f);
        float dxz = atan_fast(Ux * rz);
        float dyz = atan_fast(Uy * rz);

        float rf = __builtin_amdgcn_rcpf(fFz + 1e-10f);
        float fxz = atan_fast(fFx * rf);
        float fyz = atan_fast(fFy * rf);

        float e1 = fxz - dxz;
        float e2 = fyz - dyz;
        lsum += e1 * e1 + e2 * e2;

        #pragma unroll
        for (int f = 0; f < 2; ++f)
            #pragma unroll
            for (int q = 0; q < 4; ++q) {
                Pm[f][q] = P0[f][q];
                P0[f][q] = Pp[f][q];
            }
        fFx = nFx; fFy = nFy; fFz = nFz;
    }

    // wave shuffle -> LDS across 4 waves -> one atomic per block
    #pragma unroll
    for (int o = 32; o > 0; o >>= 1)
        lsum += __shfl_down(lsum, o, 64);
    if ((tid & 63) == 0)
        redbuf[tid >> 6] = lsum;
    __syncthreads();
    if (tid == 0) {
        float s = redbuf[0] + redbuf[1] + redbuf[2] + redbuf[3];
        atomicAdd(out, s * (1.0f / (float)NVOX));
    }
}

extern "C" void kernel_launch(void* const* d_in, const int* in_sizes, int n_in,
                              void* d_out, int out_size, void* d_ws, size_t ws_size,
                              hipStream_t stream) {
    const float* Mv   = (const float*)d_in[0];
    const float* Sv   = (const float*)d_in[1];
    const float* flow = (const float*)d_in[2];
    float* out = (float*)d_out;

    hipMemsetAsync(out, 0, sizeof(float), stream);

    dim3 grid(WW / TW, HH / TH, DD / TD);   // 5 x 24 x 20 = 2400 blocks
    demons_ori_kernel<<<grid, dim3(256), 0, stream>>>(Mv, Sv, flow, out);
}